// Round 19
// baseline (112.974 us; speedup 1.0000x reference)
//
#include <hip/hip_runtime.h>
#include <hip/hip_bf16.h>
#include <math.h>

#define N1 512
#define N2 512
#define DIN 1280
#define DD 100
#define HH 20
#define NPIX (N1*N2)
#define PB 57
#define NWIN (PB*PB)

typedef short bf16x8 __attribute__((ext_vector_type(8)));
typedef float f32x4 __attribute__((ext_vector_type(4)));

static __device__ __forceinline__ float bf16f(unsigned short u) {
  union { unsigned int i; float f; } c;
  c.i = ((unsigned int)u) << 16;
  return c.f;
}

// workspace layout in floats
static constexpr size_t WS_PP    = 0;                        // 409600
static constexpr size_t WS_W2B   = 409600;                   // pad 4096
static constexpr size_t WS_M     = 413696;                   // 20*512*512 bf16
static constexpr size_t WS_PART  = WS_M + 2621440;           // 5*262144
static constexpr size_t WS_CRAW  = WS_PART + 1310720;        // 262144
static constexpr size_t WS_STATS = WS_CRAW + 262144;         // 64
static constexpr size_t WS_B     = WS_STATS + 64;            // 57*57

// ---- projection partials (4-way K split), W1 read DIRECTLY (per-lane rows,
//      float4, lines consumed across consecutive loads; x reads wave-uniform)
//      + w2b build + stats zero (tail blocks)
__global__ __launch_bounds__(256) void kA(const float* __restrict__ x1,
                                          const float* __restrict__ x2,
                                          const float* __restrict__ W1,
                                          const float* __restrict__ W2,
                                          float* __restrict__ pp,
                                          unsigned short* __restrict__ w2b,
                                          float* __restrict__ stats) {
  const int tid = threadIdx.x;
  if (blockIdx.x >= 1024) {   // w2b + stats zero
    int idx = (blockIdx.x - 1024) * 256 + tid;
    if (blockIdx.x == 1024 && tid < 64) stats[tid] = 0.0f;
    if (idx < 224 * 32) {
      int k = idx >> 5, n = idx & 31;
      float v = (n < HH && k < 200) ? W2[n * 200 + k] : 0.0f;
      __hip_bfloat16 b = __float2bfloat16(v);
      w2b[idx] = *reinterpret_cast<unsigned short*>(&b);
    }
    return;
  }
  const int w  = __builtin_amdgcn_readfirstlane(tid >> 6);
  const int rp = w >> 1, hh = w & 1;
  const int h = hh * 64 + (tid & 63);
  if (h >= DD) return;
  const int kq = blockIdx.x & 3;
  const int r0 = (blockIdx.x >> 2) * 4 + rp * 2;
  const float* xb = (r0 < N1) ? (x1 + (size_t)r0 * DIN) : (x2 + (size_t)(r0 - N1) * DIN);
  const float* xr0 = xb + kq * 320;
  const float* xr1 = xb + DIN + kq * 320;
  const float4* wr = (const float4*)(W1 + (size_t)h * DIN + kq * 320);
  float a00 = 0.f, a01 = 0.f, a10 = 0.f, a11 = 0.f;
#pragma unroll 4
  for (int k4 = 0; k4 < 80; ++k4) {
    float4 wv = wr[k4];
    float x00 = xr0[4 * k4], x01 = xr0[4 * k4 + 1];
    float x02 = xr0[4 * k4 + 2], x03 = xr0[4 * k4 + 3];
    float x10 = xr1[4 * k4], x11 = xr1[4 * k4 + 1];
    float x12 = xr1[4 * k4 + 2], x13 = xr1[4 * k4 + 3];
    a00 = fmaf(wv.x, x00, a00); a01 = fmaf(wv.y, x01, a01);
    a00 = fmaf(wv.z, x02, a00); a01 = fmaf(wv.w, x03, a01);
    a10 = fmaf(wv.x, x10, a10); a11 = fmaf(wv.y, x11, a11);
    a10 = fmaf(wv.z, x12, a10); a11 = fmaf(wv.w, x13, a11);
  }
  pp[(size_t)kq * 102400 + (size_t)r0 * DD + h] = a00 + a01;
  pp[(size_t)kq * 102400 + (size_t)(r0 + 1) * DD + h] = a10 + a11;
}

// ---- pairwise features + FC2 via MFMA bf16 + BN1 stats; m stored bf16
//      ii-split: grid 1024 (4 blocks/CU), half = low bit; band swizzle kept
__global__ __launch_bounds__(256, 2) void kB(const float* __restrict__ pp,
                                             const float* __restrict__ b1,
                                             const unsigned short* __restrict__ w2b,
                                             unsigned short* __restrict__ m16,
                                             float* __restrict__ stats) {
  __shared__ float sA[4][132];
  __shared__ float sC[64][132];
  __shared__ float wred[4][40];
  const int tid = threadIdx.x;
  const int half = blockIdx.x & 1;
  const int rest = blockIdx.x >> 1;                     // 0..511
  const int band = rest & 7;
  const int bi = band * 8 + ((rest >> 3) & 7);
  const int bj = rest >> 6;
  const int rowBase = bi * 8 + half * 4;                // 4 i-rows this block
  for (int idx = tid; idx < 68 * 33; idx += 256) {
    int r = idx / 33, d4 = idx % 33;
    float4 v = {0.f, 0.f, 0.f, 0.f};
    if (d4 < 25) {
      size_t row = (r < 4) ? (size_t)(rowBase + r) : (size_t)(N1 + bj * 64 + (r - 4));
      const float* base = pp + row * DD;
      float4 a0 = ((const float4*)base)[d4];
      float4 a1 = ((const float4*)(base + 102400))[d4];
      float4 a2 = ((const float4*)(base + 204800))[d4];
      float4 a3 = ((const float4*)(base + 307200))[d4];
      float4 bb = ((const float4*)b1)[d4];
      v.x = a0.x + a1.x + a2.x + a3.x + bb.x;
      v.y = a0.y + a1.y + a2.y + a3.y + bb.y;
      v.z = a0.z + a1.z + a2.z + a3.z + bb.z;
      v.w = a0.w + a1.w + a2.w + a3.w + bb.w;
    }
    if (r < 4) *(float4*)&sA[r][4 * d4] = v;
    else       *(float4*)&sC[r - 4][4 * d4] = v;
  }
  __syncthreads();
  const int w = tid >> 6, lane = tid & 63;
  const int ln = lane & 15, q = lane >> 4;
  const int jj = w * 16 + ln;
  bf16x8 af[7][2];
#pragma unroll
  for (int ks = 0; ks < 7; ++ks)
#pragma unroll
    for (int t = 0; t < 2; ++t) {
      bf16x8 v;
#pragma unroll
      for (int e = 0; e < 8; ++e)
        v[e] = (short)w2b[(ks * 32 + q * 8 + e) * 32 + ln + 16 * t];
      af[ks][t] = v;
    }
  int dOf[14];
  bool isP[14];
  float4 cH[14];
#pragma unroll
  for (int hx = 0; hx < 14; ++hx) {
    int kk = (hx >> 1) * 32 + q * 8 + (hx & 1) * 4;
    isP[hx] = kk >= 100;
    dOf[hx] = isP[hx] ? kk - 100 : kk;
    cH[hx] = *(const float4*)&sC[jj][dOf[hx]];
  }
  float st_s[8], st_q[8];
#pragma unroll
  for (int r = 0; r < 8; ++r) { st_s[r] = 0.f; st_q[r] = 0.f; }
  const int gj = bj * 64 + jj;
#pragma unroll 1
  for (int ii = 0; ii < 4; ++ii) {
    bf16x8 bf[7];
#pragma unroll
    for (int ks = 0; ks < 7; ++ks) {
      float4 a0 = *(const float4*)&sA[ii][dOf[2 * ks]];
      float4 a1 = *(const float4*)&sA[ii][dOf[2 * ks + 1]];
      float4 c0 = cH[2 * ks], c1 = cH[2 * ks + 1];
      float f0 = isP[2*ks]   ? a0.x * c0.x : fabsf(a0.x - c0.x);
      float f1 = isP[2*ks]   ? a0.y * c0.y : fabsf(a0.y - c0.y);
      float f2 = isP[2*ks]   ? a0.z * c0.z : fabsf(a0.z - c0.z);
      float f3 = isP[2*ks]   ? a0.w * c0.w : fabsf(a0.w - c0.w);
      float f4 = isP[2*ks+1] ? a1.x * c1.x : fabsf(a1.x - c1.x);
      float f5 = isP[2*ks+1] ? a1.y * c1.y : fabsf(a1.y - c1.y);
      float f6 = isP[2*ks+1] ? a1.z * c1.z : fabsf(a1.z - c1.z);
      float f7 = isP[2*ks+1] ? a1.w * c1.w : fabsf(a1.w - c1.w);
      union { bf16x8 v; __hip_bfloat162 h2[4]; } u;
      u.h2[0] = __float22bfloat162_rn(make_float2(f0, f1));
      u.h2[1] = __float22bfloat162_rn(make_float2(f2, f3));
      u.h2[2] = __float22bfloat162_rn(make_float2(f4, f5));
      u.h2[3] = __float22bfloat162_rn(make_float2(f6, f7));
      bf[ks] = u.v;
    }
    f32x4 acc0 = {0.f, 0.f, 0.f, 0.f}, acc1 = {0.f, 0.f, 0.f, 0.f};
#pragma unroll
    for (int ks = 0; ks < 7; ++ks) {
      acc0 = __builtin_amdgcn_mfma_f32_16x16x32_bf16(af[ks][0], bf[ks], acc0, 0, 0, 0);
      acc1 = __builtin_amdgcn_mfma_f32_16x16x32_bf16(af[ks][1], bf[ks], acc1, 0, 0, 0);
    }
    const size_t pix = (size_t)(rowBase + ii) * N2 + gj;
#pragma unroll
    for (int r = 0; r < 4; ++r) {
      __hip_bfloat16 hb = __float2bfloat16(acc0[r]);
      m16[(size_t)(4 * q + r) * NPIX + pix] = *reinterpret_cast<unsigned short*>(&hb);
      st_s[r] += acc0[r];
      st_q[r] += acc0[r] * acc0[r];
    }
    if (q == 0) {
#pragma unroll
      for (int r = 0; r < 4; ++r) {
        __hip_bfloat16 hb = __float2bfloat16(acc1[r]);
        m16[(size_t)(16 + r) * NPIX + pix] = *reinterpret_cast<unsigned short*>(&hb);
      }
    }
#pragma unroll
    for (int r = 0; r < 4; ++r) {
      st_s[4 + r] += acc1[r];
      st_q[4 + r] += acc1[r] * acc1[r];
    }
  }
#pragma unroll
  for (int r = 0; r < 8; ++r) {
#pragma unroll
    for (int off = 1; off < 16; off <<= 1) {
      st_s[r] += __shfl_xor(st_s[r], off);
      st_q[r] += __shfl_xor(st_q[r], off);
    }
  }
  if (ln == 0) {
#pragma unroll
    for (int r = 0; r < 4; ++r) {
      wred[w][4 * q + r]      = st_s[r];
      wred[w][20 + 4 * q + r] = st_q[r];
    }
    if (q == 0) {
#pragma unroll
      for (int r = 0; r < 4; ++r) {
        wred[w][16 + r] = st_s[4 + r];
        wred[w][36 + r] = st_q[4 + r];
      }
    }
  }
  __syncthreads();
  if (tid < 40)
    atomicAdd(&stats[tid], wred[0][tid] + wred[1][tid] + wred[2][tid] + wred[3][tid]);
}

// ---- conv 7x7 v4 + XCD-band swizzle: 1D grid 1280, band = blk&7 reads its own band
__global__ __launch_bounds__(256) void kD(const unsigned short* __restrict__ m16,
                                          const float* __restrict__ bn1g,
                                          const float* __restrict__ bn1b,
                                          const float* __restrict__ cw,
                                          const float* __restrict__ stats,
                                          float* __restrict__ part) {
  __shared__ float sIn[4][22][74];
  __shared__ float sSc[4], sSh[4];
  const int tid = threadIdx.x;
  const int band = blockIdx.x & 7;
  const int rest = blockIdx.x >> 3;
  const int cs   = rest >> 5;
  const int t    = rest & 31;
  const int by   = (band * 4 + (t & 3)) * 16;
  const int bx   = (t >> 2) * 64;
  if (tid < 4) {
    int ch = cs * 4 + tid;
    float s = stats[ch], q = stats[HH + ch];
    float mu = s * (1.0f / NPIX);
    float var = q * (1.0f / NPIX) - mu * mu;
    float g = bn1g[ch] / sqrtf(var + 1e-5f);
    sSc[tid] = g;
    sSh[tid] = bn1b[ch] - mu * g;
  }
  __syncthreads();
  for (int idx = tid; idx < 4 * 22 * 18; idx += 256) {
    int ch4 = idx / (22 * 18), rem = idx % (22 * 18);
    int r = rem / 18, p = rem % 18;
    int gy = by + r - 3;
    int gx0 = bx + 4 * p - 4;
    float sc = sSc[ch4], sh = sSh[ch4];
    float v[4] = {0.f, 0.f, 0.f, 0.f};
    if (gy >= 0 && gy < N1) {
      const unsigned short* mp = m16 + (size_t)(cs * 4 + ch4) * NPIX + (size_t)gy * N2;
      if (gx0 >= 0 && gx0 + 3 < N2) {
        ushort4 u = *(const ushort4*)&mp[gx0];
        v[0] = fmaxf(fmaf(bf16f(u.x), sc, sh), 0.0f);
        v[1] = fmaxf(fmaf(bf16f(u.y), sc, sh), 0.0f);
        v[2] = fmaxf(fmaf(bf16f(u.z), sc, sh), 0.0f);
        v[3] = fmaxf(fmaf(bf16f(u.w), sc, sh), 0.0f);
      } else {
#pragma unroll
        for (int j = 0; j < 4; ++j) {
          int gx = gx0 + j;
          if (gx >= 0 && gx < N2)
            v[j] = fmaxf(fmaf(bf16f(mp[gx]), sc, sh), 0.0f);
        }
      }
    }
    *(float4*)&sIn[ch4][r][4 * p] = make_float4(v[0], v[1], v[2], v[3]);
  }
  __syncthreads();
  const int tx = tid & 31, ty = tid >> 5;
  float acc00 = 0.f, acc01 = 0.f, acc10 = 0.f, acc11 = 0.f;
#pragma unroll 1
  for (int ch4 = 0; ch4 < 4; ++ch4) {
    const float* wch = cw + (cs * 4 + ch4) * 49;
#pragma unroll
    for (int wr = 0; wr < 8; ++wr) {
      float2 rowv[5];
#pragma unroll
      for (int qq = 0; qq < 5; ++qq)
        rowv[qq] = *(const float2*)&sIn[ch4][2 * ty + wr][2 * tx + 2 * qq];
#pragma unroll
      for (int o = 0; o < 2; ++o) {
        if (wr - o < 0 || wr - o > 6) continue;
        const int ky = wr - o;
#pragma unroll
        for (int kx = 0; kx < 7; ++kx) {
          float wt = wch[ky * 7 + kx];
          const int j0 = kx + 1, j1 = kx + 2;
          float e0 = (j0 & 1) ? rowv[j0 >> 1].y : rowv[j0 >> 1].x;
          float e1 = (j1 & 1) ? rowv[j1 >> 1].y : rowv[j1 >> 1].x;
          if (o == 0) { acc00 = fmaf(e0, wt, acc00); acc01 = fmaf(e1, wt, acc01); }
          else        { acc10 = fmaf(e0, wt, acc10); acc11 = fmaf(e1, wt, acc11); }
        }
      }
    }
  }
  float* dst = part + (size_t)cs * NPIX;
  const int ox = bx + 2 * tx;
  float2 r0 = {acc00, acc01}, r1 = {acc10, acc11};
  *(float2*)&dst[(size_t)(by + 2 * ty) * N2 + ox] = r0;
  *(float2*)&dst[(size_t)(by + 2 * ty + 1) * N2 + ox] = r1;
}

// ---- sum partials -> Craw + BN2 stats; XCD-band swizzle
__global__ __launch_bounds__(256) void kE1(const float* __restrict__ part,
                                           float* __restrict__ stats,
                                           float* __restrict__ Craw) {
  __shared__ float wred[4][2];
  const int band = blockIdx.x & 7;
  const int sub  = blockIdx.x >> 3;
  const int i = ((band << 7) + sub) * 256 + threadIdx.x;
  float s5 = part[i] + part[NPIX + i] + part[2 * NPIX + i] + part[3 * NPIX + i] + part[4 * NPIX + i];
  Craw[i] = s5;
  float s = s5, q = s5 * s5;
  const int lane = threadIdx.x & 63, wv = threadIdx.x >> 6;
#pragma unroll
  for (int off = 32; off; off >>= 1) {
    s += __shfl_xor(s, off);
    q += __shfl_xor(q, off);
  }
  if (lane == 0) { wred[wv][0] = s; wred[wv][1] = q; }
  __syncthreads();
  if (threadIdx.x < 2) {
    float v = wred[0][threadIdx.x] + wred[1][threadIdx.x] + wred[2][threadIdx.x] + wred[3][threadIdx.x];
    atomicAdd(&stats[2 * HH + threadIdx.x], v);
  }
}

// ---- fused BN2 + sigmoid + maxpool
__global__ __launch_bounds__(256) void kE2M(const float* __restrict__ Craw,
                                            const float* __restrict__ stats,
                                            const float* __restrict__ bn2g,
                                            const float* __restrict__ bn2b,
                                            float* __restrict__ Cout,
                                            float* __restrict__ B) {
  const int w = blockIdx.x * 4 + (threadIdx.x >> 6);
  const int lane = threadIdx.x & 63;
  float s = stats[2 * HH], q = stats[2 * HH + 1];
  float mu = s * (1.0f / NPIX);
  float var = q * (1.0f / NPIX) - mu * mu;
  float g = bn2g[0] / sqrtf(var + 1e-5f);
  float b = bn2b[0] - mu * g;
  if (w >= NWIN) return;
  const int wy = w / PB, wx = w % PB;
  const int y0 = wy * 9 - 4, x0 = wx * 9 - 4;
  float mx = -1e30f;
  for (int e = lane; e < 144; e += 64) {
    int dy = e / 12, dx = e % 12;
    int y = y0 + dy, x = x0 + dx;
    bool inWin = (dy < 9) && (dx < 9);
    bool claim = (y >= 0) && (y < N1) && (x >= 0) && (x < N2) &&
                 (dy < 9 || wy == PB - 1) && (dx < 9 || wx == PB - 1);
    if (claim) {
      float z = Craw[(size_t)y * N2 + x] * g + b;
      float sg = 1.0f / (1.0f + expf(-z));
      Cout[(size_t)y * N2 + x] = sg;
      if (inWin) mx = fmaxf(mx, sg);
    }
  }
#pragma unroll
  for (int off = 32; off; off >>= 1) mx = fmaxf(mx, __shfl_xor(mx, off));
  if (lane == 0) B[w] = mx;
}

// ---- per-column mean/std(ddof=1), phat -> d_out[0]
__global__ __launch_bounds__(1024) void kF(const float* __restrict__ B,
                                           const float* __restrict__ gamma,
                                           float* __restrict__ out0) {
  __shared__ float sB[NWIN];
  __shared__ float cm[PB], cs[PB];
  __shared__ float r1[16], r2[16];
  const int tid = threadIdx.x;
  for (int i = tid; i < NWIN; i += 1024) sB[i] = B[i];
  __syncthreads();
  if (tid < PB * 16) {
    int c = tid >> 4, g = tid & 15;
    float s = 0.0f;
    for (int h = g; h < PB; h += 16) s += sB[h * PB + c];
#pragma unroll
    for (int off = 1; off < 16; off <<= 1) s += __shfl_xor(s, off);
    float mean = s / (float)PB;
    float v = 0.0f;
    for (int h = g; h < PB; h += 16) { float d = sB[h * PB + c] - mean; v += d * d; }
#pragma unroll
    for (int off = 1; off < 16; off <<= 1) v += __shfl_xor(v, off);
    if (g == 0) {
      cm[c] = mean;
      cs[c] = sqrtf(v / (float)(PB - 1) + 1e-5f);
    }
  }
  __syncthreads();
  const float g = gamma[0];
  float sq = 0.0f, cnt = 0.0f;
  for (int i = tid; i < NWIN; i += 1024) {
    int w = i % PB;
    float qv = sB[i] - cm[w] - g * cs[w];
    if (qv > 0.0f) { sq += qv; cnt += 1.0f; }
  }
#pragma unroll
  for (int off = 32; off; off >>= 1) {
    sq += __shfl_xor(sq, off);
    cnt += __shfl_xor(cnt, off);
  }
  if ((tid & 63) == 0) { r1[tid >> 6] = sq; r2[tid >> 6] = cnt; }
  __syncthreads();
  if (tid == 0) {
    float S = 0.f, Cn = 0.f;
#pragma unroll
    for (int e = 0; e < 16; ++e) { S += r1[e]; Cn += r2[e]; }
    float phat = S / (Cn + 1.0f);
    float sig = 1.0f / (1.0f + expf(-phat));
    out0[0] = fminf(fmaxf(sig, 0.0f), 1.0f);
  }
}

extern "C" void kernel_launch(void* const* d_in, const int* in_sizes, int n_in,
                              void* d_out, int out_size, void* d_ws, size_t ws_size,
                              hipStream_t stream) {
  const float* x1    = (const float*)d_in[0];
  const float* x2    = (const float*)d_in[1];
  const float* W1    = (const float*)d_in[2];
  const float* b1    = (const float*)d_in[3];
  const float* W2    = (const float*)d_in[4];
  // d_in[5] = b2   : cancels through BN1 (training-mode mean subtraction)
  const float* bn1g  = (const float*)d_in[6];
  const float* bn1b  = (const float*)d_in[7];
  const float* convw = (const float*)d_in[8];
  // d_in[9] = conv_b : cancels through BN2
  const float* bn2g  = (const float*)d_in[10];
  const float* bn2b  = (const float*)d_in[11];
  const float* gamma = (const float*)d_in[12];

  float* ws    = (float*)d_ws;
  float* pp    = ws + WS_PP;
  unsigned short* w2b = (unsigned short*)(ws + WS_W2B);
  unsigned short* m16 = (unsigned short*)(ws + WS_M);
  float* part  = ws + WS_PART;
  float* Craw  = ws + WS_CRAW;
  float* stats = ws + WS_STATS;
  float* Bp    = ws + WS_B;
  float* out   = (float*)d_out;

  kA<<<1052, 256, 0, stream>>>(x1, x2, W1, W2, pp, w2b, stats);
  kB<<<1024, 256, 0, stream>>>(pp, b1, w2b, m16, stats);
  kD<<<1280, 256, 0, stream>>>(m16, bn1g, bn1b, convw, stats, part);
  kE1<<<1024, 256, 0, stream>>>(part, stats, Craw);
  kE2M<<<(NWIN + 3) / 4, 256, 0, stream>>>(Craw, stats, bn2g, bn2b, out + 1, Bp);
  kF<<<1, 1024, 0, stream>>>(Bp, gamma, out);
}

// Round 20
// 100.459 us; speedup vs baseline: 1.1246x; 1.1246x over previous
//
#include <hip/hip_runtime.h>
#include <hip/hip_bf16.h>
#include <math.h>

#define N1 512
#define N2 512
#define DIN 1280
#define DD 100
#define HH 20
#define NPIX (N1*N2)
#define PB 57
#define NWIN (PB*PB)

typedef short bf16x8 __attribute__((ext_vector_type(8)));
typedef float f32x4 __attribute__((ext_vector_type(4)));

static __device__ __forceinline__ float bf16f(unsigned short u) {
  union { unsigned int i; float f; } c;
  c.i = ((unsigned int)u) << 16;
  return c.f;
}

// workspace layout in floats
static constexpr size_t WS_PP    = 0;                        // 409600
static constexpr size_t WS_W1T   = 409600;                   // 128000
static constexpr size_t WS_W2B   = 537600;                   // pad 4096
static constexpr size_t WS_M     = 541696;                   // 20*512*512 bf16
static constexpr size_t WS_PART  = WS_M + 2621440;           // 5*262144
static constexpr size_t WS_CRAW  = WS_PART + 1310720;        // 262144
static constexpr size_t WS_STATS = WS_CRAW + 262144;         // 64
static constexpr size_t WS_B     = WS_STATS + 64;            // 57*57

// ---- prologue: transpose W1 -> w1t[k][h]  (coalesced both sides — do NOT remove:
//      per-lane-row W1 reads cost +25 µs, measured R6 and re-measured R19)
__global__ __launch_bounds__(256) void kP(const float* __restrict__ W1,
                                          float* __restrict__ w1t) {
  const int tid = threadIdx.x;
  __shared__ float sT[32][33];
  const int bx = blockIdx.x % 40, by = blockIdx.x / 40;
  const int tx = tid & 31, ty = tid >> 5;
#pragma unroll
  for (int e = 0; e < 4; ++e) {
    int h = by * 32 + ty + e * 8, k = bx * 32 + tx;
    sT[ty + e * 8][tx] = (h < DD) ? W1[(size_t)h * DIN + k] : 0.0f;
  }
  __syncthreads();
#pragma unroll
  for (int e = 0; e < 4; ++e) {
    int k = bx * 32 + ty + e * 8, h = by * 32 + tx;
    if (h < DD) w1t[(size_t)k * DD + h] = sT[tx][ty + e * 8];
  }
}

// ---- projection partials (4-way K split) via w1t + w2b build + stats zero
__global__ __launch_bounds__(256) void kA(const float* __restrict__ x1,
                                          const float* __restrict__ x2,
                                          const float* __restrict__ w1t,
                                          const float* __restrict__ W2,
                                          float* __restrict__ pp,
                                          unsigned short* __restrict__ w2b,
                                          float* __restrict__ stats) {
  const int tid = threadIdx.x;
  if (blockIdx.x >= 1024) {   // w2b + stats zero
    int idx = (blockIdx.x - 1024) * 256 + tid;
    if (blockIdx.x == 1024 && tid < 64) stats[tid] = 0.0f;
    if (idx < 224 * 32) {
      int k = idx >> 5, n = idx & 31;
      float v = (n < HH && k < 200) ? W2[n * 200 + k] : 0.0f;
      __hip_bfloat16 b = __float2bfloat16(v);
      w2b[idx] = *reinterpret_cast<unsigned short*>(&b);
    }
    return;
  }
  const int w  = __builtin_amdgcn_readfirstlane(tid >> 6);
  const int rp = w >> 1, hh = w & 1;
  const int h = hh * 64 + (tid & 63);
  if (h >= DD) return;
  const int kq = blockIdx.x & 3;
  const int r0 = (blockIdx.x >> 2) * 4 + rp * 2;
  const float* xb = (r0 < N1) ? (x1 + (size_t)r0 * DIN) : (x2 + (size_t)(r0 - N1) * DIN);
  const float* xr0 = xb + kq * 320;
  const float* xr1 = xb + DIN + kq * 320;
  const float* w1p = w1t + (size_t)kq * 320 * DD + h;
  float a00 = 0.f, a01 = 0.f, a10 = 0.f, a11 = 0.f;
#pragma unroll 8
  for (int k = 0; k < 320; k += 2) {
    float wA = w1p[(size_t)k * DD];
    float wB = w1p[(size_t)(k + 1) * DD];
    a00 = fmaf(wA, xr0[k], a00); a01 = fmaf(wB, xr0[k + 1], a01);
    a10 = fmaf(wA, xr1[k], a10); a11 = fmaf(wB, xr1[k + 1], a11);
  }
  pp[(size_t)kq * 102400 + (size_t)r0 * DD + h] = a00 + a01;
  pp[(size_t)kq * 102400 + (size_t)(r0 + 1) * DD + h] = a10 + a11;
}

// ---- pairwise features + FC2 via MFMA bf16 + BN1 stats; m stored bf16
//      ii-split: grid 1024 (4 blocks/CU); XCD band swizzle kept
__global__ __launch_bounds__(256, 2) void kB(const float* __restrict__ pp,
                                             const float* __restrict__ b1,
                                             const unsigned short* __restrict__ w2b,
                                             unsigned short* __restrict__ m16,
                                             float* __restrict__ stats) {
  __shared__ float sA[4][132];
  __shared__ float sC[64][132];
  __shared__ float wred[4][40];
  const int tid = threadIdx.x;
  const int half = blockIdx.x & 1;
  const int rest = blockIdx.x >> 1;                     // 0..511
  const int band = rest & 7;
  const int bi = band * 8 + ((rest >> 3) & 7);
  const int bj = rest >> 6;
  const int rowBase = bi * 8 + half * 4;                // 4 i-rows this block
  for (int idx = tid; idx < 68 * 33; idx += 256) {
    int r = idx / 33, d4 = idx % 33;
    float4 v = {0.f, 0.f, 0.f, 0.f};
    if (d4 < 25) {
      size_t row = (r < 4) ? (size_t)(rowBase + r) : (size_t)(N1 + bj * 64 + (r - 4));
      const float* base = pp + row * DD;
      float4 a0 = ((const float4*)base)[d4];
      float4 a1 = ((const float4*)(base + 102400))[d4];
      float4 a2 = ((const float4*)(base + 204800))[d4];
      float4 a3 = ((const float4*)(base + 307200))[d4];
      float4 bb = ((const float4*)b1)[d4];
      v.x = a0.x + a1.x + a2.x + a3.x + bb.x;
      v.y = a0.y + a1.y + a2.y + a3.y + bb.y;
      v.z = a0.z + a1.z + a2.z + a3.z + bb.z;
      v.w = a0.w + a1.w + a2.w + a3.w + bb.w;
    }
    if (r < 4) *(float4*)&sA[r][4 * d4] = v;
    else       *(float4*)&sC[r - 4][4 * d4] = v;
  }
  __syncthreads();
  const int w = tid >> 6, lane = tid & 63;
  const int ln = lane & 15, q = lane >> 4;
  const int jj = w * 16 + ln;
  bf16x8 af[7][2];
#pragma unroll
  for (int ks = 0; ks < 7; ++ks)
#pragma unroll
    for (int t = 0; t < 2; ++t) {
      bf16x8 v;
#pragma unroll
      for (int e = 0; e < 8; ++e)
        v[e] = (short)w2b[(ks * 32 + q * 8 + e) * 32 + ln + 16 * t];
      af[ks][t] = v;
    }
  int dOf[14];
  bool isP[14];
  float4 cH[14];
#pragma unroll
  for (int hx = 0; hx < 14; ++hx) {
    int kk = (hx >> 1) * 32 + q * 8 + (hx & 1) * 4;
    isP[hx] = kk >= 100;
    dOf[hx] = isP[hx] ? kk - 100 : kk;
    cH[hx] = *(const float4*)&sC[jj][dOf[hx]];
  }
  float st_s[8], st_q[8];
#pragma unroll
  for (int r = 0; r < 8; ++r) { st_s[r] = 0.f; st_q[r] = 0.f; }
  const int gj = bj * 64 + jj;
#pragma unroll 1
  for (int ii = 0; ii < 4; ++ii) {
    bf16x8 bf[7];
#pragma unroll
    for (int ks = 0; ks < 7; ++ks) {
      float4 a0 = *(const float4*)&sA[ii][dOf[2 * ks]];
      float4 a1 = *(const float4*)&sA[ii][dOf[2 * ks + 1]];
      float4 c0 = cH[2 * ks], c1 = cH[2 * ks + 1];
      float f0 = isP[2*ks]   ? a0.x * c0.x : fabsf(a0.x - c0.x);
      float f1 = isP[2*ks]   ? a0.y * c0.y : fabsf(a0.y - c0.y);
      float f2 = isP[2*ks]   ? a0.z * c0.z : fabsf(a0.z - c0.z);
      float f3 = isP[2*ks]   ? a0.w * c0.w : fabsf(a0.w - c0.w);
      float f4 = isP[2*ks+1] ? a1.x * c1.x : fabsf(a1.x - c1.x);
      float f5 = isP[2*ks+1] ? a1.y * c1.y : fabsf(a1.y - c1.y);
      float f6 = isP[2*ks+1] ? a1.z * c1.z : fabsf(a1.z - c1.z);
      float f7 = isP[2*ks+1] ? a1.w * c1.w : fabsf(a1.w - c1.w);
      union { bf16x8 v; __hip_bfloat162 h2[4]; } u;
      u.h2[0] = __float22bfloat162_rn(make_float2(f0, f1));
      u.h2[1] = __float22bfloat162_rn(make_float2(f2, f3));
      u.h2[2] = __float22bfloat162_rn(make_float2(f4, f5));
      u.h2[3] = __float22bfloat162_rn(make_float2(f6, f7));
      bf[ks] = u.v;
    }
    f32x4 acc0 = {0.f, 0.f, 0.f, 0.f}, acc1 = {0.f, 0.f, 0.f, 0.f};
#pragma unroll
    for (int ks = 0; ks < 7; ++ks) {
      acc0 = __builtin_amdgcn_mfma_f32_16x16x32_bf16(af[ks][0], bf[ks], acc0, 0, 0, 0);
      acc1 = __builtin_amdgcn_mfma_f32_16x16x32_bf16(af[ks][1], bf[ks], acc1, 0, 0, 0);
    }
    const size_t pix = (size_t)(rowBase + ii) * N2 + gj;
#pragma unroll
    for (int r = 0; r < 4; ++r) {
      __hip_bfloat16 hb = __float2bfloat16(acc0[r]);
      m16[(size_t)(4 * q + r) * NPIX + pix] = *reinterpret_cast<unsigned short*>(&hb);
      st_s[r] += acc0[r];
      st_q[r] += acc0[r] * acc0[r];
    }
    if (q == 0) {
#pragma unroll
      for (int r = 0; r < 4; ++r) {
        __hip_bfloat16 hb = __float2bfloat16(acc1[r]);
        m16[(size_t)(16 + r) * NPIX + pix] = *reinterpret_cast<unsigned short*>(&hb);
      }
    }
#pragma unroll
    for (int r = 0; r < 4; ++r) {
      st_s[4 + r] += acc1[r];
      st_q[4 + r] += acc1[r] * acc1[r];
    }
  }
#pragma unroll
  for (int r = 0; r < 8; ++r) {
#pragma unroll
    for (int off = 1; off < 16; off <<= 1) {
      st_s[r] += __shfl_xor(st_s[r], off);
      st_q[r] += __shfl_xor(st_q[r], off);
    }
  }
  if (ln == 0) {
#pragma unroll
    for (int r = 0; r < 4; ++r) {
      wred[w][4 * q + r]      = st_s[r];
      wred[w][20 + 4 * q + r] = st_q[r];
    }
    if (q == 0) {
#pragma unroll
      for (int r = 0; r < 4; ++r) {
        wred[w][16 + r] = st_s[4 + r];
        wred[w][36 + r] = st_q[4 + r];
      }
    }
  }
  __syncthreads();
  if (tid < 40)
    atomicAdd(&stats[tid], wred[0][tid] + wred[1][tid] + wred[2][tid] + wred[3][tid]);
}

// ---- conv 7x7 v4 + XCD-band swizzle: 1D grid 1280, band = blk&7 reads its own band
__global__ __launch_bounds__(256) void kD(const unsigned short* __restrict__ m16,
                                          const float* __restrict__ bn1g,
                                          const float* __restrict__ bn1b,
                                          const float* __restrict__ cw,
                                          const float* __restrict__ stats,
                                          float* __restrict__ part) {
  __shared__ float sIn[4][22][74];
  __shared__ float sSc[4], sSh[4];
  const int tid = threadIdx.x;
  const int band = blockIdx.x & 7;
  const int rest = blockIdx.x >> 3;
  const int cs   = rest >> 5;
  const int t    = rest & 31;
  const int by   = (band * 4 + (t & 3)) * 16;
  const int bx   = (t >> 2) * 64;
  if (tid < 4) {
    int ch = cs * 4 + tid;
    float s = stats[ch], q = stats[HH + ch];
    float mu = s * (1.0f / NPIX);
    float var = q * (1.0f / NPIX) - mu * mu;
    float g = bn1g[ch] / sqrtf(var + 1e-5f);
    sSc[tid] = g;
    sSh[tid] = bn1b[ch] - mu * g;
  }
  __syncthreads();
  for (int idx = tid; idx < 4 * 22 * 18; idx += 256) {
    int ch4 = idx / (22 * 18), rem = idx % (22 * 18);
    int r = rem / 18, p = rem % 18;
    int gy = by + r - 3;
    int gx0 = bx + 4 * p - 4;
    float sc = sSc[ch4], sh = sSh[ch4];
    float v[4] = {0.f, 0.f, 0.f, 0.f};
    if (gy >= 0 && gy < N1) {
      const unsigned short* mp = m16 + (size_t)(cs * 4 + ch4) * NPIX + (size_t)gy * N2;
      if (gx0 >= 0 && gx0 + 3 < N2) {
        ushort4 u = *(const ushort4*)&mp[gx0];
        v[0] = fmaxf(fmaf(bf16f(u.x), sc, sh), 0.0f);
        v[1] = fmaxf(fmaf(bf16f(u.y), sc, sh), 0.0f);
        v[2] = fmaxf(fmaf(bf16f(u.z), sc, sh), 0.0f);
        v[3] = fmaxf(fmaf(bf16f(u.w), sc, sh), 0.0f);
      } else {
#pragma unroll
        for (int j = 0; j < 4; ++j) {
          int gx = gx0 + j;
          if (gx >= 0 && gx < N2)
            v[j] = fmaxf(fmaf(bf16f(mp[gx]), sc, sh), 0.0f);
        }
      }
    }
    *(float4*)&sIn[ch4][r][4 * p] = make_float4(v[0], v[1], v[2], v[3]);
  }
  __syncthreads();
  const int tx = tid & 31, ty = tid >> 5;
  float acc00 = 0.f, acc01 = 0.f, acc10 = 0.f, acc11 = 0.f;
#pragma unroll 1
  for (int ch4 = 0; ch4 < 4; ++ch4) {
    const float* wch = cw + (cs * 4 + ch4) * 49;
#pragma unroll
    for (int wr = 0; wr < 8; ++wr) {
      float2 rowv[5];
#pragma unroll
      for (int qq = 0; qq < 5; ++qq)
        rowv[qq] = *(const float2*)&sIn[ch4][2 * ty + wr][2 * tx + 2 * qq];
#pragma unroll
      for (int o = 0; o < 2; ++o) {
        if (wr - o < 0 || wr - o > 6) continue;
        const int ky = wr - o;
#pragma unroll
        for (int kx = 0; kx < 7; ++kx) {
          float wt = wch[ky * 7 + kx];
          const int j0 = kx + 1, j1 = kx + 2;
          float e0 = (j0 & 1) ? rowv[j0 >> 1].y : rowv[j0 >> 1].x;
          float e1 = (j1 & 1) ? rowv[j1 >> 1].y : rowv[j1 >> 1].x;
          if (o == 0) { acc00 = fmaf(e0, wt, acc00); acc01 = fmaf(e1, wt, acc01); }
          else        { acc10 = fmaf(e0, wt, acc10); acc11 = fmaf(e1, wt, acc11); }
        }
      }
    }
  }
  float* dst = part + (size_t)cs * NPIX;
  const int ox = bx + 2 * tx;
  float2 r0 = {acc00, acc01}, r1 = {acc10, acc11};
  *(float2*)&dst[(size_t)(by + 2 * ty) * N2 + ox] = r0;
  *(float2*)&dst[(size_t)(by + 2 * ty + 1) * N2 + ox] = r1;
}

// ---- sum partials -> Craw + BN2 stats; XCD-band swizzle
__global__ __launch_bounds__(256) void kE1(const float* __restrict__ part,
                                           float* __restrict__ stats,
                                           float* __restrict__ Craw) {
  __shared__ float wred[4][2];
  const int band = blockIdx.x & 7;
  const int sub  = blockIdx.x >> 3;
  const int i = ((band << 7) + sub) * 256 + threadIdx.x;
  float s5 = part[i] + part[NPIX + i] + part[2 * NPIX + i] + part[3 * NPIX + i] + part[4 * NPIX + i];
  Craw[i] = s5;
  float s = s5, q = s5 * s5;
  const int lane = threadIdx.x & 63, wv = threadIdx.x >> 6;
#pragma unroll
  for (int off = 32; off; off >>= 1) {
    s += __shfl_xor(s, off);
    q += __shfl_xor(q, off);
  }
  if (lane == 0) { wred[wv][0] = s; wred[wv][1] = q; }
  __syncthreads();
  if (threadIdx.x < 2) {
    float v = wred[0][threadIdx.x] + wred[1][threadIdx.x] + wred[2][threadIdx.x] + wred[3][threadIdx.x];
    atomicAdd(&stats[2 * HH + threadIdx.x], v);
  }
}

// ---- fused BN2 + sigmoid + maxpool
__global__ __launch_bounds__(256) void kE2M(const float* __restrict__ Craw,
                                            const float* __restrict__ stats,
                                            const float* __restrict__ bn2g,
                                            const float* __restrict__ bn2b,
                                            float* __restrict__ Cout,
                                            float* __restrict__ B) {
  const int w = blockIdx.x * 4 + (threadIdx.x >> 6);
  const int lane = threadIdx.x & 63;
  float s = stats[2 * HH], q = stats[2 * HH + 1];
  float mu = s * (1.0f / NPIX);
  float var = q * (1.0f / NPIX) - mu * mu;
  float g = bn2g[0] / sqrtf(var + 1e-5f);
  float b = bn2b[0] - mu * g;
  if (w >= NWIN) return;
  const int wy = w / PB, wx = w % PB;
  const int y0 = wy * 9 - 4, x0 = wx * 9 - 4;
  float mx = -1e30f;
  for (int e = lane; e < 144; e += 64) {
    int dy = e / 12, dx = e % 12;
    int y = y0 + dy, x = x0 + dx;
    bool inWin = (dy < 9) && (dx < 9);
    bool claim = (y >= 0) && (y < N1) && (x >= 0) && (x < N2) &&
                 (dy < 9 || wy == PB - 1) && (dx < 9 || wx == PB - 1);
    if (claim) {
      float z = Craw[(size_t)y * N2 + x] * g + b;
      float sg = 1.0f / (1.0f + expf(-z));
      Cout[(size_t)y * N2 + x] = sg;
      if (inWin) mx = fmaxf(mx, sg);
    }
  }
#pragma unroll
  for (int off = 32; off; off >>= 1) mx = fmaxf(mx, __shfl_xor(mx, off));
  if (lane == 0) B[w] = mx;
}

// ---- per-column mean/std(ddof=1), phat -> d_out[0]
__global__ __launch_bounds__(1024) void kF(const float* __restrict__ B,
                                           const float* __restrict__ gamma,
                                           float* __restrict__ out0) {
  __shared__ float sB[NWIN];
  __shared__ float cm[PB], cs[PB];
  __shared__ float r1[16], r2[16];
  const int tid = threadIdx.x;
  for (int i = tid; i < NWIN; i += 1024) sB[i] = B[i];
  __syncthreads();
  if (tid < PB * 16) {
    int c = tid >> 4, g = tid & 15;
    float s = 0.0f;
    for (int h = g; h < PB; h += 16) s += sB[h * PB + c];
#pragma unroll
    for (int off = 1; off < 16; off <<= 1) s += __shfl_xor(s, off);
    float mean = s / (float)PB;
    float v = 0.0f;
    for (int h = g; h < PB; h += 16) { float d = sB[h * PB + c] - mean; v += d * d; }
#pragma unroll
    for (int off = 1; off < 16; off <<= 1) v += __shfl_xor(v, off);
    if (g == 0) {
      cm[c] = mean;
      cs[c] = sqrtf(v / (float)(PB - 1) + 1e-5f);
    }
  }
  __syncthreads();
  const float g = gamma[0];
  float sq = 0.0f, cnt = 0.0f;
  for (int i = tid; i < NWIN; i += 1024) {
    int w = i % PB;
    float qv = sB[i] - cm[w] - g * cs[w];
    if (qv > 0.0f) { sq += qv; cnt += 1.0f; }
  }
#pragma unroll
  for (int off = 32; off; off >>= 1) {
    sq += __shfl_xor(sq, off);
    cnt += __shfl_xor(cnt, off);
  }
  if ((tid & 63) == 0) { r1[tid >> 6] = sq; r2[tid >> 6] = cnt; }
  __syncthreads();
  if (tid == 0) {
    float S = 0.f, Cn = 0.f;
#pragma unroll
    for (int e = 0; e < 16; ++e) { S += r1[e]; Cn += r2[e]; }
    float phat = S / (Cn + 1.0f);
    float sig = 1.0f / (1.0f + expf(-phat));
    out0[0] = fminf(fmaxf(sig, 0.0f), 1.0f);
  }
}

extern "C" void kernel_launch(void* const* d_in, const int* in_sizes, int n_in,
                              void* d_out, int out_size, void* d_ws, size_t ws_size,
                              hipStream_t stream) {
  const float* x1    = (const float*)d_in[0];
  const float* x2    = (const float*)d_in[1];
  const float* W1    = (const float*)d_in[2];
  const float* b1    = (const float*)d_in[3];
  const float* W2    = (const float*)d_in[4];
  // d_in[5] = b2   : cancels through BN1 (training-mode mean subtraction)
  const float* bn1g  = (const float*)d_in[6];
  const float* bn1b  = (const float*)d_in[7];
  const float* convw = (const float*)d_in[8];
  // d_in[9] = conv_b : cancels through BN2
  const float* bn2g  = (const float*)d_in[10];
  const float* bn2b  = (const float*)d_in[11];
  const float* gamma = (const float*)d_in[12];

  float* ws    = (float*)d_ws;
  float* pp    = ws + WS_PP;
  float* w1t   = ws + WS_W1T;
  unsigned short* w2b = (unsigned short*)(ws + WS_W2B);
  unsigned short* m16 = (unsigned short*)(ws + WS_M);
  float* part  = ws + WS_PART;
  float* Craw  = ws + WS_CRAW;
  float* stats = ws + WS_STATS;
  float* Bp    = ws + WS_B;
  float* out   = (float*)d_out;

  kP<<<160, 256, 0, stream>>>(W1, w1t);
  kA<<<1052, 256, 0, stream>>>(x1, x2, w1t, W2, pp, w2b, stats);
  kB<<<1024, 256, 0, stream>>>(pp, b1, w2b, m16, stats);
  kD<<<1280, 256, 0, stream>>>(m16, bn1g, bn1b, convw, stats, part);
  kE1<<<1024, 256, 0, stream>>>(part, stats, Craw);
  kE2M<<<(NWIN + 3) / 4, 256, 0, stream>>>(Craw, stats, bn2g, bn2b, out + 1, Bp);
  kF<<<1, 1024, 0, stream>>>(Bp, gamma, out);
}

// Round 21
// 88.288 us; speedup vs baseline: 1.2796x; 1.1379x over previous
//
#include <hip/hip_runtime.h>
#include <hip/hip_bf16.h>
#include <math.h>

#define N1 512
#define N2 512
#define DIN 1280
#define DD 100
#define HH 20
#define NPIX (N1*N2)
#define PB 57
#define NWIN (PB*PB)

typedef short bf16x8 __attribute__((ext_vector_type(8)));
typedef float f32x4 __attribute__((ext_vector_type(4)));

static __device__ __forceinline__ float bf16f(unsigned short u) {
  union { unsigned int i; float f; } c;
  c.i = ((unsigned int)u) << 16;
  return c.f;
}

// workspace layout in floats
static constexpr size_t WS_PP    = 0;                        // 409600
static constexpr size_t WS_W1T   = 409600;                   // 128000
static constexpr size_t WS_W2B   = 537600;                   // pad 4096
static constexpr size_t WS_M     = 541696;                   // 20*512*512 bf16
static constexpr size_t WS_PART  = WS_M + 2621440;           // 5*262144
static constexpr size_t WS_CRAW  = WS_PART + 1310720;        // 262144
static constexpr size_t WS_STATS = WS_CRAW + 262144;         // 64
static constexpr size_t WS_B     = WS_STATS + 64;            // 57*57

// ---- prologue: transpose W1 -> w1t[k][h]  (coalesced both sides — do NOT remove:
//      per-lane-row W1 reads cost +25 µs, measured R6 and re-measured R19)
__global__ __launch_bounds__(256) void kP(const float* __restrict__ W1,
                                          float* __restrict__ w1t) {
  const int tid = threadIdx.x;
  __shared__ float sT[32][33];
  const int bx = blockIdx.x % 40, by = blockIdx.x / 40;
  const int tx = tid & 31, ty = tid >> 5;
#pragma unroll
  for (int e = 0; e < 4; ++e) {
    int h = by * 32 + ty + e * 8, k = bx * 32 + tx;
    sT[ty + e * 8][tx] = (h < DD) ? W1[(size_t)h * DIN + k] : 0.0f;
  }
  __syncthreads();
#pragma unroll
  for (int e = 0; e < 4; ++e) {
    int k = bx * 32 + ty + e * 8, h = by * 32 + tx;
    if (h < DD) w1t[(size_t)k * DD + h] = sT[tx][ty + e * 8];
  }
}

// ---- projection partials (4-way K split) via w1t + w2b build + stats zero
__global__ __launch_bounds__(256) void kA(const float* __restrict__ x1,
                                          const float* __restrict__ x2,
                                          const float* __restrict__ w1t,
                                          const float* __restrict__ W2,
                                          float* __restrict__ pp,
                                          unsigned short* __restrict__ w2b,
                                          float* __restrict__ stats) {
  const int tid = threadIdx.x;
  if (blockIdx.x >= 1024) {   // w2b + stats zero
    int idx = (blockIdx.x - 1024) * 256 + tid;
    if (blockIdx.x == 1024 && tid < 64) stats[tid] = 0.0f;
    if (idx < 224 * 32) {
      int k = idx >> 5, n = idx & 31;
      float v = (n < HH && k < 200) ? W2[n * 200 + k] : 0.0f;
      __hip_bfloat16 b = __float2bfloat16(v);
      w2b[idx] = *reinterpret_cast<unsigned short*>(&b);
    }
    return;
  }
  const int w  = __builtin_amdgcn_readfirstlane(tid >> 6);
  const int rp = w >> 1, hh = w & 1;
  const int h = hh * 64 + (tid & 63);
  if (h >= DD) return;
  const int kq = blockIdx.x & 3;
  const int r0 = (blockIdx.x >> 2) * 4 + rp * 2;
  const float* xb = (r0 < N1) ? (x1 + (size_t)r0 * DIN) : (x2 + (size_t)(r0 - N1) * DIN);
  const float* xr0 = xb + kq * 320;
  const float* xr1 = xb + DIN + kq * 320;
  const float* w1p = w1t + (size_t)kq * 320 * DD + h;
  float a00 = 0.f, a01 = 0.f, a10 = 0.f, a11 = 0.f;
#pragma unroll 8
  for (int k = 0; k < 320; k += 2) {
    float wA = w1p[(size_t)k * DD];
    float wB = w1p[(size_t)(k + 1) * DD];
    a00 = fmaf(wA, xr0[k], a00); a01 = fmaf(wB, xr0[k + 1], a01);
    a10 = fmaf(wA, xr1[k], a10); a11 = fmaf(wB, xr1[k + 1], a11);
  }
  pp[(size_t)kq * 102400 + (size_t)r0 * DD + h] = a00 + a01;
  pp[(size_t)kq * 102400 + (size_t)(r0 + 1) * DD + h] = a10 + a11;
}

// ---- pairwise features + FC2 via MFMA bf16 + BN1 stats; m stored bf16
//      R18 form: grid 512, 8-row sA; XCD band swizzle
__global__ __launch_bounds__(256, 2) void kB(const float* __restrict__ pp,
                                             const float* __restrict__ b1,
                                             const unsigned short* __restrict__ w2b,
                                             unsigned short* __restrict__ m16,
                                             float* __restrict__ stats) {
  __shared__ float sA[8][132];
  __shared__ float sC[64][132];
  __shared__ float wred[4][40];
  const int tid = threadIdx.x;
  const int band = blockIdx.x & 7;
  const int bi = band * 8 + ((blockIdx.x >> 3) & 7);   // rows bi*8 in band*64..+64
  const int bj = blockIdx.x >> 6;
  for (int idx = tid; idx < 72 * 33; idx += 256) {
    int r = idx / 33, d4 = idx % 33;
    float4 v = {0.f, 0.f, 0.f, 0.f};
    if (d4 < 25) {
      size_t row = (r < 8) ? (size_t)(bi * 8 + r) : (size_t)(N1 + bj * 64 + (r - 8));
      const float* base = pp + row * DD;
      float4 a0 = ((const float4*)base)[d4];
      float4 a1 = ((const float4*)(base + 102400))[d4];
      float4 a2 = ((const float4*)(base + 204800))[d4];
      float4 a3 = ((const float4*)(base + 307200))[d4];
      float4 bb = ((const float4*)b1)[d4];
      v.x = a0.x + a1.x + a2.x + a3.x + bb.x;
      v.y = a0.y + a1.y + a2.y + a3.y + bb.y;
      v.z = a0.z + a1.z + a2.z + a3.z + bb.z;
      v.w = a0.w + a1.w + a2.w + a3.w + bb.w;
    }
    if (r < 8) *(float4*)&sA[r][4 * d4] = v;
    else       *(float4*)&sC[r - 8][4 * d4] = v;
  }
  __syncthreads();
  const int w = tid >> 6, lane = tid & 63;
  const int ln = lane & 15, q = lane >> 4;
  const int jj = w * 16 + ln;
  bf16x8 af[7][2];
#pragma unroll
  for (int ks = 0; ks < 7; ++ks)
#pragma unroll
    for (int t = 0; t < 2; ++t) {
      bf16x8 v;
#pragma unroll
      for (int e = 0; e < 8; ++e)
        v[e] = (short)w2b[(ks * 32 + q * 8 + e) * 32 + ln + 16 * t];
      af[ks][t] = v;
    }
  int dOf[14];
  bool isP[14];
  float4 cH[14];
#pragma unroll
  for (int hx = 0; hx < 14; ++hx) {
    int kk = (hx >> 1) * 32 + q * 8 + (hx & 1) * 4;
    isP[hx] = kk >= 100;
    dOf[hx] = isP[hx] ? kk - 100 : kk;
    cH[hx] = *(const float4*)&sC[jj][dOf[hx]];
  }
  float st_s[8], st_q[8];
#pragma unroll
  for (int r = 0; r < 8; ++r) { st_s[r] = 0.f; st_q[r] = 0.f; }
  const int gj = bj * 64 + jj;
#pragma unroll 1
  for (int ii = 0; ii < 8; ++ii) {
    bf16x8 bf[7];
#pragma unroll
    for (int ks = 0; ks < 7; ++ks) {
      float4 a0 = *(const float4*)&sA[ii][dOf[2 * ks]];
      float4 a1 = *(const float4*)&sA[ii][dOf[2 * ks + 1]];
      float4 c0 = cH[2 * ks], c1 = cH[2 * ks + 1];
      float f0 = isP[2*ks]   ? a0.x * c0.x : fabsf(a0.x - c0.x);
      float f1 = isP[2*ks]   ? a0.y * c0.y : fabsf(a0.y - c0.y);
      float f2 = isP[2*ks]   ? a0.z * c0.z : fabsf(a0.z - c0.z);
      float f3 = isP[2*ks]   ? a0.w * c0.w : fabsf(a0.w - c0.w);
      float f4 = isP[2*ks+1] ? a1.x * c1.x : fabsf(a1.x - c1.x);
      float f5 = isP[2*ks+1] ? a1.y * c1.y : fabsf(a1.y - c1.y);
      float f6 = isP[2*ks+1] ? a1.z * c1.z : fabsf(a1.z - c1.z);
      float f7 = isP[2*ks+1] ? a1.w * c1.w : fabsf(a1.w - c1.w);
      union { bf16x8 v; __hip_bfloat162 h2[4]; } u;
      u.h2[0] = __float22bfloat162_rn(make_float2(f0, f1));
      u.h2[1] = __float22bfloat162_rn(make_float2(f2, f3));
      u.h2[2] = __float22bfloat162_rn(make_float2(f4, f5));
      u.h2[3] = __float22bfloat162_rn(make_float2(f6, f7));
      bf[ks] = u.v;
    }
    f32x4 acc0 = {0.f, 0.f, 0.f, 0.f}, acc1 = {0.f, 0.f, 0.f, 0.f};
#pragma unroll
    for (int ks = 0; ks < 7; ++ks) {
      acc0 = __builtin_amdgcn_mfma_f32_16x16x32_bf16(af[ks][0], bf[ks], acc0, 0, 0, 0);
      acc1 = __builtin_amdgcn_mfma_f32_16x16x32_bf16(af[ks][1], bf[ks], acc1, 0, 0, 0);
    }
    const size_t pix = (size_t)(bi * 8 + ii) * N2 + gj;
#pragma unroll
    for (int r = 0; r < 4; ++r) {
      __hip_bfloat16 hb = __float2bfloat16(acc0[r]);
      m16[(size_t)(4 * q + r) * NPIX + pix] = *reinterpret_cast<unsigned short*>(&hb);
      st_s[r] += acc0[r];
      st_q[r] += acc0[r] * acc0[r];
    }
    if (q == 0) {
#pragma unroll
      for (int r = 0; r < 4; ++r) {
        __hip_bfloat16 hb = __float2bfloat16(acc1[r]);
        m16[(size_t)(16 + r) * NPIX + pix] = *reinterpret_cast<unsigned short*>(&hb);
      }
    }
#pragma unroll
    for (int r = 0; r < 4; ++r) {
      st_s[4 + r] += acc1[r];
      st_q[4 + r] += acc1[r] * acc1[r];
    }
  }
#pragma unroll
  for (int r = 0; r < 8; ++r) {
#pragma unroll
    for (int off = 1; off < 16; off <<= 1) {
      st_s[r] += __shfl_xor(st_s[r], off);
      st_q[r] += __shfl_xor(st_q[r], off);
    }
  }
  if (ln == 0) {
#pragma unroll
    for (int r = 0; r < 4; ++r) {
      wred[w][4 * q + r]      = st_s[r];
      wred[w][20 + 4 * q + r] = st_q[r];
    }
    if (q == 0) {
#pragma unroll
      for (int r = 0; r < 4; ++r) {
        wred[w][16 + r] = st_s[4 + r];
        wred[w][36 + r] = st_q[4 + r];
      }
    }
  }
  __syncthreads();
  if (tid < 40)
    atomicAdd(&stats[tid], wred[0][tid] + wred[1][tid] + wred[2][tid] + wred[3][tid]);
}

// ---- conv 7x7 v4 + XCD-band swizzle: 1D grid 1280, band = blk&7 reads its own band
__global__ __launch_bounds__(256) void kD(const unsigned short* __restrict__ m16,
                                          const float* __restrict__ bn1g,
                                          const float* __restrict__ bn1b,
                                          const float* __restrict__ cw,
                                          const float* __restrict__ stats,
                                          float* __restrict__ part) {
  __shared__ float sIn[4][22][74];
  __shared__ float sSc[4], sSh[4];
  const int tid = threadIdx.x;
  const int band = blockIdx.x & 7;
  const int rest = blockIdx.x >> 3;
  const int cs   = rest >> 5;
  const int t    = rest & 31;
  const int by   = (band * 4 + (t & 3)) * 16;
  const int bx   = (t >> 2) * 64;
  if (tid < 4) {
    int ch = cs * 4 + tid;
    float s = stats[ch], q = stats[HH + ch];
    float mu = s * (1.0f / NPIX);
    float var = q * (1.0f / NPIX) - mu * mu;
    float g = bn1g[ch] / sqrtf(var + 1e-5f);
    sSc[tid] = g;
    sSh[tid] = bn1b[ch] - mu * g;
  }
  __syncthreads();
  for (int idx = tid; idx < 4 * 22 * 18; idx += 256) {
    int ch4 = idx / (22 * 18), rem = idx % (22 * 18);
    int r = rem / 18, p = rem % 18;
    int gy = by + r - 3;
    int gx0 = bx + 4 * p - 4;
    float sc = sSc[ch4], sh = sSh[ch4];
    float v[4] = {0.f, 0.f, 0.f, 0.f};
    if (gy >= 0 && gy < N1) {
      const unsigned short* mp = m16 + (size_t)(cs * 4 + ch4) * NPIX + (size_t)gy * N2;
      if (gx0 >= 0 && gx0 + 3 < N2) {
        ushort4 u = *(const ushort4*)&mp[gx0];
        v[0] = fmaxf(fmaf(bf16f(u.x), sc, sh), 0.0f);
        v[1] = fmaxf(fmaf(bf16f(u.y), sc, sh), 0.0f);
        v[2] = fmaxf(fmaf(bf16f(u.z), sc, sh), 0.0f);
        v[3] = fmaxf(fmaf(bf16f(u.w), sc, sh), 0.0f);
      } else {
#pragma unroll
        for (int j = 0; j < 4; ++j) {
          int gx = gx0 + j;
          if (gx >= 0 && gx < N2)
            v[j] = fmaxf(fmaf(bf16f(mp[gx]), sc, sh), 0.0f);
        }
      }
    }
    *(float4*)&sIn[ch4][r][4 * p] = make_float4(v[0], v[1], v[2], v[3]);
  }
  __syncthreads();
  const int tx = tid & 31, ty = tid >> 5;
  float acc00 = 0.f, acc01 = 0.f, acc10 = 0.f, acc11 = 0.f;
#pragma unroll 1
  for (int ch4 = 0; ch4 < 4; ++ch4) {
    const float* wch = cw + (cs * 4 + ch4) * 49;
#pragma unroll
    for (int wr = 0; wr < 8; ++wr) {
      float2 rowv[5];
#pragma unroll
      for (int qq = 0; qq < 5; ++qq)
        rowv[qq] = *(const float2*)&sIn[ch4][2 * ty + wr][2 * tx + 2 * qq];
#pragma unroll
      for (int o = 0; o < 2; ++o) {
        if (wr - o < 0 || wr - o > 6) continue;
        const int ky = wr - o;
#pragma unroll
        for (int kx = 0; kx < 7; ++kx) {
          float wt = wch[ky * 7 + kx];
          const int j0 = kx + 1, j1 = kx + 2;
          float e0 = (j0 & 1) ? rowv[j0 >> 1].y : rowv[j0 >> 1].x;
          float e1 = (j1 & 1) ? rowv[j1 >> 1].y : rowv[j1 >> 1].x;
          if (o == 0) { acc00 = fmaf(e0, wt, acc00); acc01 = fmaf(e1, wt, acc01); }
          else        { acc10 = fmaf(e0, wt, acc10); acc11 = fmaf(e1, wt, acc11); }
        }
      }
    }
  }
  float* dst = part + (size_t)cs * NPIX;
  const int ox = bx + 2 * tx;
  float2 r0 = {acc00, acc01}, r1 = {acc10, acc11};
  *(float2*)&dst[(size_t)(by + 2 * ty) * N2 + ox] = r0;
  *(float2*)&dst[(size_t)(by + 2 * ty + 1) * N2 + ox] = r1;
}

// ---- sum partials -> Craw + BN2 stats; XCD-band swizzle
__global__ __launch_bounds__(256) void kE1(const float* __restrict__ part,
                                           float* __restrict__ stats,
                                           float* __restrict__ Craw) {
  __shared__ float wred[4][2];
  const int band = blockIdx.x & 7;
  const int sub  = blockIdx.x >> 3;
  const int i = ((band << 7) + sub) * 256 + threadIdx.x;
  float s5 = part[i] + part[NPIX + i] + part[2 * NPIX + i] + part[3 * NPIX + i] + part[4 * NPIX + i];
  Craw[i] = s5;
  float s = s5, q = s5 * s5;
  const int lane = threadIdx.x & 63, wv = threadIdx.x >> 6;
#pragma unroll
  for (int off = 32; off; off >>= 1) {
    s += __shfl_xor(s, off);
    q += __shfl_xor(q, off);
  }
  if (lane == 0) { wred[wv][0] = s; wred[wv][1] = q; }
  __syncthreads();
  if (threadIdx.x < 2) {
    float v = wred[0][threadIdx.x] + wred[1][threadIdx.x] + wred[2][threadIdx.x] + wred[3][threadIdx.x];
    atomicAdd(&stats[2 * HH + threadIdx.x], v);
  }
}

// ---- fused BN2 + sigmoid + maxpool
__global__ __launch_bounds__(256) void kE2M(const float* __restrict__ Craw,
                                            const float* __restrict__ stats,
                                            const float* __restrict__ bn2g,
                                            const float* __restrict__ bn2b,
                                            float* __restrict__ Cout,
                                            float* __restrict__ B) {
  const int w = blockIdx.x * 4 + (threadIdx.x >> 6);
  const int lane = threadIdx.x & 63;
  float s = stats[2 * HH], q = stats[2 * HH + 1];
  float mu = s * (1.0f / NPIX);
  float var = q * (1.0f / NPIX) - mu * mu;
  float g = bn2g[0] / sqrtf(var + 1e-5f);
  float b = bn2b[0] - mu * g;
  if (w >= NWIN) return;
  const int wy = w / PB, wx = w % PB;
  const int y0 = wy * 9 - 4, x0 = wx * 9 - 4;
  float mx = -1e30f;
  for (int e = lane; e < 144; e += 64) {
    int dy = e / 12, dx = e % 12;
    int y = y0 + dy, x = x0 + dx;
    bool inWin = (dy < 9) && (dx < 9);
    bool claim = (y >= 0) && (y < N1) && (x >= 0) && (x < N2) &&
                 (dy < 9 || wy == PB - 1) && (dx < 9 || wx == PB - 1);
    if (claim) {
      float z = Craw[(size_t)y * N2 + x] * g + b;
      float sg = 1.0f / (1.0f + expf(-z));
      Cout[(size_t)y * N2 + x] = sg;
      if (inWin) mx = fmaxf(mx, sg);
    }
  }
#pragma unroll
  for (int off = 32; off; off >>= 1) mx = fmaxf(mx, __shfl_xor(mx, off));
  if (lane == 0) B[w] = mx;
}

// ---- per-column mean/std(ddof=1), phat -> d_out[0]
__global__ __launch_bounds__(1024) void kF(const float* __restrict__ B,
                                           const float* __restrict__ gamma,
                                           float* __restrict__ out0) {
  __shared__ float sB[NWIN];
  __shared__ float cm[PB], cs[PB];
  __shared__ float r1[16], r2[16];
  const int tid = threadIdx.x;
  for (int i = tid; i < NWIN; i += 1024) sB[i] = B[i];
  __syncthreads();
  if (tid < PB * 16) {
    int c = tid >> 4, g = tid & 15;
    float s = 0.0f;
    for (int h = g; h < PB; h += 16) s += sB[h * PB + c];
#pragma unroll
    for (int off = 1; off < 16; off <<= 1) s += __shfl_xor(s, off);
    float mean = s / (float)PB;
    float v = 0.0f;
    for (int h = g; h < PB; h += 16) { float d = sB[h * PB + c] - mean; v += d * d; }
#pragma unroll
    for (int off = 1; off < 16; off <<= 1) v += __shfl_xor(v, off);
    if (g == 0) {
      cm[c] = mean;
      cs[c] = sqrtf(v / (float)(PB - 1) + 1e-5f);
    }
  }
  __syncthreads();
  const float g = gamma[0];
  float sq = 0.0f, cnt = 0.0f;
  for (int i = tid; i < NWIN; i += 1024) {
    int w = i % PB;
    float qv = sB[i] - cm[w] - g * cs[w];
    if (qv > 0.0f) { sq += qv; cnt += 1.0f; }
  }
#pragma unroll
  for (int off = 32; off; off >>= 1) {
    sq += __shfl_xor(sq, off);
    cnt += __shfl_xor(cnt, off);
  }
  if ((tid & 63) == 0) { r1[tid >> 6] = sq; r2[tid >> 6] = cnt; }
  __syncthreads();
  if (tid == 0) {
    float S = 0.f, Cn = 0.f;
#pragma unroll
    for (int e = 0; e < 16; ++e) { S += r1[e]; Cn += r2[e]; }
    float phat = S / (Cn + 1.0f);
    float sig = 1.0f / (1.0f + expf(-phat));
    out0[0] = fminf(fmaxf(sig, 0.0f), 1.0f);
  }
}

extern "C" void kernel_launch(void* const* d_in, const int* in_sizes, int n_in,
                              void* d_out, int out_size, void* d_ws, size_t ws_size,
                              hipStream_t stream) {
  const float* x1    = (const float*)d_in[0];
  const float* x2    = (const float*)d_in[1];
  const float* W1    = (const float*)d_in[2];
  const float* b1    = (const float*)d_in[3];
  const float* W2    = (const float*)d_in[4];
  // d_in[5] = b2   : cancels through BN1 (training-mode mean subtraction)
  const float* bn1g  = (const float*)d_in[6];
  const float* bn1b  = (const float*)d_in[7];
  const float* convw = (const float*)d_in[8];
  // d_in[9] = conv_b : cancels through BN2
  const float* bn2g  = (const float*)d_in[10];
  const float* bn2b  = (const float*)d_in[11];
  const float* gamma = (const float*)d_in[12];

  float* ws    = (float*)d_ws;
  float* pp    = ws + WS_PP;
  float* w1t   = ws + WS_W1T;
  unsigned short* w2b = (unsigned short*)(ws + WS_W2B);
  unsigned short* m16 = (unsigned short*)(ws + WS_M);
  float* part  = ws + WS_PART;
  float* Craw  = ws + WS_CRAW;
  float* stats = ws + WS_STATS;
  float* Bp    = ws + WS_B;
  float* out   = (float*)d_out;

  kP<<<160, 256, 0, stream>>>(W1, w1t);
  kA<<<1052, 256, 0, stream>>>(x1, x2, w1t, W2, pp, w2b, stats);
  kB<<<512, 256, 0, stream>>>(pp, b1, w2b, m16, stats);
  kD<<<1280, 256, 0, stream>>>(m16, bn1g, bn1b, convw, stats, part);
  kE1<<<1024, 256, 0, stream>>>(part, stats, Craw);
  kE2M<<<(NWIN + 3) / 4, 256, 0, stream>>>(Craw, stats, bn2g, bn2b, out + 1, Bp);
  kF<<<1, 1024, 0, stream>>>(Bp, gamma, out);
}